// Round 4
// baseline (25119.292 us; speedup 1.0000x reference)
//
#include <hip/hip_runtime.h>
#include <stdint.h>

#define S_LEN 8192
#define DIM   2048
#define W2    4096   // W row length = 2*DIM

typedef __attribute__((ext_vector_type(8))) __bf16 bf16x8;
typedef __attribute__((ext_vector_type(4))) float  floatx4;
typedef unsigned long long u64;
typedef unsigned int       u32;

// ---------------------------------------------------------------------------
// Init: tag buffers. buf0 = s_0 = -1.0 with tag 0; buf1 tag 0 (never matches
// its first expected tag 1, so readers spin until written).
// ---------------------------------------------------------------------------
__global__ void init_pairs(u64* __restrict__ pairs) {
  int i = blockIdx.x * 256 + threadIdx.x;
  if (i < 2 * DIM) {
    pairs[i] = ((u64)__float_as_uint(-1.0f) << 32) | 0ull;
  }
}

// ---------------------------------------------------------------------------
// GEMM: C[m][n] = sum_k A[m][k] * W[n*4096 + 2048 + k] + b[n]   (unchanged)
// ---------------------------------------------------------------------------
__device__ inline bf16x8 pack_bf8(float4 a, float4 b) {
  bf16x8 h;
  h[0] = (__bf16)a.x; h[1] = (__bf16)a.y; h[2] = (__bf16)a.z; h[3] = (__bf16)a.w;
  h[4] = (__bf16)b.x; h[5] = (__bf16)b.y; h[6] = (__bf16)b.z; h[7] = (__bf16)b.w;
  return h;
}

__global__ __launch_bounds__(256) void gemm_ctx(const float* __restrict__ A,
                                                const float* __restrict__ W,
                                                const float* __restrict__ bias,
                                                float* __restrict__ C) {
  __shared__ __bf16 As[64][72];
  __shared__ __bf16 Bs[64][72];
  const int tid  = threadIdx.x;
  const int m0   = blockIdx.y * 64;
  const int n0   = blockIdx.x * 64;
  const int w    = tid >> 6;
  const int lane = tid & 63;
  const int wm   = w >> 1, wn = w & 1;
  const int r    = tid >> 2;
  const int seg  = tid & 3;

  floatx4 acc[2][2] = {};

  for (int k0 = 0; k0 < DIM; k0 += 64) {
    {
      const float* pa = A + (size_t)(m0 + r) * DIM + k0 + seg * 16;
      const float* pb = W + (size_t)(n0 + r) * W2 + DIM + k0 + seg * 16;
      float4 a0 = ((const float4*)pa)[0], a1 = ((const float4*)pa)[1];
      float4 a2 = ((const float4*)pa)[2], a3 = ((const float4*)pa)[3];
      float4 b0 = ((const float4*)pb)[0], b1 = ((const float4*)pb)[1];
      float4 b2 = ((const float4*)pb)[2], b3 = ((const float4*)pb)[3];
      *(bf16x8*)&As[r][seg * 16]     = pack_bf8(a0, a1);
      *(bf16x8*)&As[r][seg * 16 + 8] = pack_bf8(a2, a3);
      *(bf16x8*)&Bs[r][seg * 16]     = pack_bf8(b0, b1);
      *(bf16x8*)&Bs[r][seg * 16 + 8] = pack_bf8(b2, b3);
    }
    __syncthreads();
    #pragma unroll
    for (int kk = 0; kk < 64; kk += 32) {
      const int ks = kk + (lane >> 4) * 8;
      bf16x8 af[2], bfr[2];
      af[0]  = *(const bf16x8*)&As[32 * wm +      (lane & 15)][ks];
      af[1]  = *(const bf16x8*)&As[32 * wm + 16 + (lane & 15)][ks];
      bfr[0] = *(const bf16x8*)&Bs[32 * wn +      (lane & 15)][ks];
      bfr[1] = *(const bf16x8*)&Bs[32 * wn + 16 + (lane & 15)][ks];
      #pragma unroll
      for (int im = 0; im < 2; ++im)
        #pragma unroll
        for (int in = 0; in < 2; ++in)
          acc[im][in] = __builtin_amdgcn_mfma_f32_16x16x32_bf16(
              af[im], bfr[in], acc[im][in], 0, 0, 0);
    }
    __syncthreads();
  }

  #pragma unroll
  for (int in = 0; in < 2; ++in) {
    const int col = n0 + 32 * wn + 16 * in + (lane & 15);
    const float bv = bias[col];
    #pragma unroll
    for (int im = 0; im < 2; ++im) {
      const int rbase = m0 + 32 * wm + 16 * im + (lane >> 4) * 4;
      #pragma unroll
      for (int q = 0; q < 4; ++q)
        C[(size_t)(rbase + q) * DIM + col] = acc[im][in][q] + bv;
    }
  }
}

// ---------------------------------------------------------------------------
// Persistent recurrence v4: 64 WGs x 1024 threads (16 waves). WG k owns rows
// [32k,32k+32); wave w owns rows i0+2w, i0+2w+1; lane l owns cols [32l,32l+32).
// v4 changes vs v3 (VGPR_Count=88 proved W was spilled to scratch):
//   - 1024-thread WGs: per-lane W = 64 fp32 (16 float4). A 1024-thread block
//     must fit 4 waves/SIMD => hard 128-VGPR cap; 64+~40 fits, spilling W
//     gains nothing.
//   - asm pin INSIDE the t-loop: reload-per-iteration now has explicit cost;
//     keeping W live in VGPRs is the allocator's cheapest option.
// ---------------------------------------------------------------------------
__global__ __launch_bounds__(1024, 1) void recur(const float* __restrict__ W,
                                                 const float* __restrict__ ce,
                                                 float* __restrict__ out,
                                                 u64* __restrict__ pairs) {
  __shared__ __align__(16) float st[DIM];
  const int tid = threadIdx.x;
  const int w = tid >> 6, l = tid & 63;
  const int i0 = blockIdx.x * 32;

  // W slab: 2 rows x 32 cols fp32 per lane = 16 float4 = 64 VGPRs.
  float4 wv[16];
  #pragma unroll
  for (int r2 = 0; r2 < 2; ++r2) {
    const float4* wp = (const float4*)(W + (size_t)(i0 + 2 * w + r2) * W2 + 32 * l);
    #pragma unroll
    for (int j = 0; j < 8; ++j) wv[r2 * 8 + j] = wp[j];
  }

  const int myrow = i0 + 2 * w + l;  // valid when l < 2
  const bool owner = (l < 2);
  float hcm = -3.0e38f;              // running cummax
  float s_last = 0.f;
  u64* b0 = pairs;
  u64* b1 = pairs + DIM;
  const int base = tid * 2;          // 1024 threads x 2 entries = 2048
  // physical slot for logical index 2*tid (XOR swizzle consistent with read)
  const int slot2 = (2 * tid) ^ (((tid >> 4) & 7) << 2);

  // step-1 operands (prefetched before the loop)
  float cev = 0.f, cxv = 0.f;
  if (owner) {
    cev = ce[myrow];
    cxv = out[myrow];
  }

  for (int t = 1; t <= S_LEN; ++t) {
    // ---- poll: all 2048 tags of s_{t-1} in buf[(t-1)&1] ----
    u64* src = ((t - 1) & 1) ? b1 : b0;
    const u32 want = (u32)(t - 1);
    u64 v0 = __hip_atomic_load(&src[base], __ATOMIC_RELAXED,
                               __HIP_MEMORY_SCOPE_AGENT);
    u64 v1 = __hip_atomic_load(&src[base + 1], __ATOMIC_RELAXED,
                               __HIP_MEMORY_SCOPE_AGENT);
    for (;;) {
      bool bad0 = ((u32)v0 != want);
      bool bad1 = ((u32)v1 != want);
      if (!(bad0 || bad1)) break;
      if (bad0) v0 = __hip_atomic_load(&src[base], __ATOMIC_RELAXED,
                                       __HIP_MEMORY_SCOPE_AGENT);
      if (bad1) v1 = __hip_atomic_load(&src[base + 1], __ATOMIC_RELAXED,
                                       __HIP_MEMORY_SCOPE_AGENT);
    }

    // ---- issue NEXT step's stream loads (resolve during next poll) ----
    float ncev = 0.f, ncxv = 0.f;
    if (owner && t < S_LEN) {
      ncev = ce[(size_t)t * DIM + myrow];
      ncxv = out[(size_t)t * DIM + myrow];
    }

    __syncthreads();  // prior-iteration LDS reads complete
    {
      float2 sv2;
      sv2.x = __uint_as_float((u32)(v0 >> 32));
      sv2.y = __uint_as_float((u32)(v1 >> 32));
      *(float2*)&st[slot2] = sv2;
    }
    __syncthreads();

    // ---- pin W in VGPRs: in-loop opaque asm makes spilling cost a reload
    #pragma unroll
    for (int i = 0; i < 16; ++i)
      asm volatile("" : "+v"(wv[i].x), "+v"(wv[i].y), "+v"(wv[i].z), "+v"(wv[i].w));

    // ---- y partial: 2 rows x 32 cols per lane ----
    float a0 = 0.f, a1 = 0.f;
    #pragma unroll
    for (int jj = 0; jj < 8; ++jj) {
      const float4 sv = *(const float4*)&st[32 * l + 4 * (jj ^ (l & 7))];
      a0 = fmaf(wv[    jj].x, sv.x, a0); a0 = fmaf(wv[    jj].y, sv.y, a0);
      a0 = fmaf(wv[    jj].z, sv.z, a0); a0 = fmaf(wv[    jj].w, sv.w, a0);
      a1 = fmaf(wv[8 + jj].x, sv.x, a1); a1 = fmaf(wv[8 + jj].y, sv.y, a1);
      a1 = fmaf(wv[8 + jj].z, sv.z, a1); a1 = fmaf(wv[8 + jj].w, sv.w, a1);
    }

    // ---- 64-lane butterfly reduce ----
    #pragma unroll
    for (int m = 1; m < 64; m <<= 1) {
      a0 += __shfl_xor(a0, m, 64);
      a1 += __shfl_xor(a1, m, 64);
    }

    if (owner) {
      float y = (l == 0 ? a0 : a1) + cxv;
      hcm = fmaxf(hcm, cev);
      float s = hcm * (1.0f / (1.0f + __expf(-y)));
      // tag store FIRST — it is the critical path for every other WG
      u64* dst = (t & 1) ? b1 : b0;
      u64 pk = ((u64)__float_as_uint(s) << 32) | (u64)(u32)t;
      __hip_atomic_store(&dst[myrow], pk, __ATOMIC_RELAXED,
                         __HIP_MEMORY_SCOPE_AGENT);
      out[(size_t)(t - 1) * DIM + myrow] = s;
      s_last = s;
    }
    cev = ncev;
    cxv = ncxv;
  }

  if (owner) out[(size_t)S_LEN * DIM + myrow] = s_last;
}

// ---------------------------------------------------------------------------
extern "C" void kernel_launch(void* const* d_in, const int* in_sizes, int n_in,
                              void* d_out, int out_size, void* d_ws, size_t ws_size,
                              hipStream_t stream) {
  const float* ce = (const float*)d_in[0];
  const float* W  = (const float*)d_in[1];
  const float* b  = (const float*)d_in[2];
  float* out = (float*)d_out;
  u64* pairs = (u64*)d_ws;   // 2 * 2048 * 8B = 32 KB

  hipLaunchKernelGGL(init_pairs, dim3(16), dim3(256), 0, stream, pairs);
  hipLaunchKernelGGL(gemm_ctx, dim3(DIM / 64, S_LEN / 64), dim3(256), 0, stream,
                     ce, W, b, out);
  hipLaunchKernelGGL(recur, dim3(64), dim3(1024), 0, stream, W, ce, out, pairs);
}